// Round 18
// baseline (383.732 us; speedup 1.0000x reference)
//
#include <hip/hip_runtime.h>
#include <hip/hip_bf16.h>
#include <stdint.h>

#define BB 16
#define CC 256
#define NN 2048
#define KK 10
#define WW 128
#define DELTA 0.10f

typedef unsigned short ushort_t;
typedef __attribute__((ext_vector_type(8))) _Float16 half8;
typedef __attribute__((ext_vector_type(4))) _Float16 half4;
typedef __attribute__((ext_vector_type(8))) short short8;
typedef __attribute__((ext_vector_type(4))) float f32x4;

// converted-weight table offsets (fp32 elements)
#define TW1_O 0
#define TB1_O 32768
#define TW2_O 32896
#define TB2_O 34432
#define TW3_O 34560
#define TB3_O 67328
#define SW1_O 67584
#define SB1_O 133120
#define SW2_O 133248
#define SB2_O 133760
#define SW3_O 133888
#define SB3_O 166656

__device__ __forceinline__ float bflo(unsigned p){ union{unsigned u; float f;} v; v.u = p << 16; return v.f; }
__device__ __forceinline__ float bfhi(unsigned p){ union{unsigned u; float f;} v; v.u = p & 0xffff0000u; return v.f; }
__device__ __forceinline__ float bfs(ushort_t u){ union{unsigned u; float f;} v; v.u = ((unsigned)u) << 16; return v.f; }
__device__ __forceinline__ ushort_t f2bf16(float f){
  __hip_bfloat16 h = __float2bfloat16(f);
  return *reinterpret_cast<ushort_t*>(&h);
}
__device__ __forceinline__ uint2 f4_to_bf4(float4 v){
  uint2 r;
  r.x = (unsigned)f2bf16(v.x) | ((unsigned)f2bf16(v.y) << 16);
  r.y = (unsigned)f2bf16(v.z) | ((unsigned)f2bf16(v.w) << 16);
  return r;
}
__device__ __forceinline__ float max4(f32x4 v){ return fmaxf(fmaxf(v[0],v[1]), fmaxf(v[2],v[3])); }

// packed screen key: sortable-uint(value) high 21 bits | j-index low 11 bits
__device__ __forceinline__ unsigned packkey(float k, int j){
  unsigned u = __float_as_uint(k);
  unsigned s = u ^ (unsigned)(((int)u >> 31) | (int)0x80000000);
  return (s & 0xFFFFF800u) | (unsigned)j;
}
__device__ __forceinline__ float unpackval(unsigned p){
  unsigned s = p & 0xFFFFF800u;
  unsigned u = (s & 0x80000000u) ? (s & 0x7FFFFFFFu) : ~s;
  return __uint_as_float(u);
}

// wave-parallel input-dtype probe: fp32 data read as bf16 pairs -> garbage exponents.
__device__ __forceinline__ int detect_isf(const void* xraw, int lane){
  unsigned u = ((const unsigned*)xraw)[lane];
  float a = fabsf(bflo(u)), c = fabsf(bfhi(u));
  if(!(a < 1e30f)) a = 1e30f;
  if(!(c < 1e30f)) c = 1e30f;
  float m = fmaxf(a, c);
  #pragma unroll
  for(int off = 32; off > 0; off >>= 1) m = fmaxf(m, __shfl_xor(m, off));
  return m > 1e3f;   // 1 => inputs are fp32
}

// ---------------- D1: convert all weights/biases to fp32 table ----------------
__global__ void k_convw(const void* xraw,
                        const void* p0, const void* p1, const void* p2, const void* p3,
                        const void* p4, const void* p5, const void* p6, const void* p7,
                        const void* p8, const void* p9, const void* p10, const void* p11,
                        float* __restrict__ dst){
  const int counts[12] = {32768,128,1536,128,32768,256,65536,128,512,128,32768,256};
  const int offs[12]   = {TW1_O,TB1_O,TW2_O,TB2_O,TW3_O,TB3_O,SW1_O,SB1_O,SW2_O,SB2_O,SW3_O,SB3_O};
  int a = blockIdx.y;
  const void* src;
  switch(a){
    case 0: src=p0; break; case 1: src=p1; break; case 2: src=p2; break;
    case 3: src=p3; break; case 4: src=p4; break; case 5: src=p5; break;
    case 6: src=p6; break; case 7: src=p7; break; case 8: src=p8; break;
    case 9: src=p9; break; case 10: src=p10; break; default: src=p11; break;
  }
  int isf = detect_isf(xraw, threadIdx.x & 63);
  int cnt = counts[a], off = offs[a];
  for(int i = blockIdx.x*256 + threadIdx.x; i < cnt; i += gridDim.x*256){
    float v = isf ? ((const float*)src)[i] : bfs(((const ushort_t*)src)[i]);
    dst[off + i] = v;
  }
}

// ---------------- D1b: pack {sw1_nbr, sw1_ctr, tw1} fp16 + sw3 bf16 + tw3 fp16 ----------------
__global__ void k_convwh(const float* __restrict__ Wc, ushort_t* __restrict__ Wh,
                         ushort_t* __restrict__ Wh3, ushort_t* __restrict__ Wh3t){
  int o = blockIdx.x;
  int t = threadIdx.x;   // 0..255
  if(o < 384){
    float v;
    if(o < 128)      v = Wc[SW1_O + o*512 + t];            // sw1 neighbor part
    else if(o < 256) v = Wc[SW1_O + (o-128)*512 + 256 + t];// sw1 center part
    else             v = Wc[TW1_O + (o-256)*256 + t];      // tw1
    _Float16 h = (_Float16)v;
    Wh[(size_t)o*CC + t] = *reinterpret_cast<ushort_t*>(&h);
  } else if(o < 512){
    // sw3 (256 x 128, row-major) -> bf16, linear copy
    int i = (o - 384)*256 + t;   // 0..32767
    Wh3[i] = f2bf16(Wc[SW3_O + i]);
  } else {
    // tw3 (256 x 128, row-major) -> fp16, linear copy
    int i = (o - 512)*256 + t;   // 0..32767
    _Float16 h = (_Float16)Wc[TW3_O + i];
    Wh3t[i] = *reinterpret_cast<ushort_t*>(&h);
  }
}

// ---------------- D2: canonicalize x -> xT fp32 (B,N,C) + fp16 copy ----------------
__global__ void k_convx(const void* __restrict__ xraw,
                        float* __restrict__ xT, ushort_t* __restrict__ xTh){
  __shared__ float tile[32][33];
  int tx = threadIdx.x, ty = threadIdx.y;
  int isf = detect_isf(xraw, (ty*32 + tx) & 63);
  int b = blockIdx.z;
  int n0 = blockIdx.x * 32;
  int c0 = blockIdx.y * 32;
  #pragma unroll
  for(int r = 0; r < 4; r++){
    int c = c0 + ty + r*8;
    size_t off = ((size_t)b*CC + c)*NN + n0 + tx;
    float v = isf ? ((const float*)xraw)[off] : bfs(((const ushort_t*)xraw)[off]);
    tile[ty + r*8][tx] = v;
  }
  __syncthreads();
  #pragma unroll
  for(int r = 0; r < 4; r++){
    int n = n0 + ty + r*8;
    size_t off = ((size_t)b*NN + n)*CC + c0 + tx;
    float v = tile[tx][ty + r*8];
    xT[off] = v;
    _Float16 h = (_Float16)v;
    xTh[off] = *reinterpret_cast<ushort_t*>(&h);
  }
}

// ---------------- K1: row norms (fp64 + fp32 copy) ----------------
__global__ void k_norms(const float* __restrict__ xT, double* __restrict__ xx,
                        float* __restrict__ xxf){
  int row = blockIdx.x*4 + (threadIdx.x >> 6);
  int lane = threadIdx.x & 63;
  float4 q = *(const float4*)(xT + (size_t)row*CC + lane*4);
  double s = (double)q.x*q.x + (double)q.y*q.y + (double)q.z*q.z + (double)q.w*q.w;
  #pragma unroll
  for(int off = 32; off > 0; off >>= 1) s += __shfl_down(s, off);
  if(lane == 0){ xx[row] = s; xxf[row] = (float)s; }
}

// ---------------- K2a: kNN screen v12 — 64 i-rows + med3 + r3-style double-buffer ----------------
// grid (B, N/64); block 256 (4 waves), 2 blocks/CU. Empirical minimum of the
// config sweep (128i/1w=110us, 64i/2w=91.6, 64i/2w+dbuf=84.8, 32i-jsplit/3w=151.8,
// 32i/4w=141). acc LOCAL to the combined mfma+screen lambda (r8/r9 miscompile
// had acc in outer scope shared between separate lambdas — do not do that).
__global__ __launch_bounds__(256, 2) void k_knn(
    const ushort_t* __restrict__ xTh, const float* __restrict__ xxf,
    unsigned* __restrict__ knnP){
  __shared__ float xxs[2048];
  const int t    = threadIdx.x;
  const int lane = t & 63;
  const int w    = t >> 6;
  const int b    = blockIdx.x;
  const int i0   = blockIdx.y * 64;
  const size_t xb = (size_t)b * NN;
  const int l15  = lane & 15;
  const int q    = lane >> 4;

  // stage shifted norms (key = 2*dot - (xx - 256): shrinks |key| for packing)
  for(int e = t; e < 2048; e += 256) xxs[e] = xxf[xb + e] - 256.0f;

  // B-frags: xi rows i0..i0+63 (four 16-row halves), fp16, K=256: 128 regs
  half8 bx[4][8];
  #pragma unroll
  for(int h = 0; h < 4; h++){
    const ushort_t* pi = xTh + (xb + i0 + h*16 + l15)*CC + q*8;
    #pragma unroll
    for(int ks = 0; ks < 8; ks++) bx[h][ks] = *(const half8*)(pi + ks*32);
  }

  unsigned lst[4][11];
  #pragma unroll
  for(int h = 0; h < 4; h++)
    #pragma unroll
    for(int k2 = 0; k2 < 11; k2++) lst[h][k2] = 0u;

  __syncthreads();

  const int arow = w*16 + l15;        // this lane's A-frag row within a jc-tile
  #define APTR(JC) (xTh + (xb + (size_t)(JC)*64 + arow)*CC + q*8)

  // MFMA + med3 screen for one jc-tile; acc strictly local to this lambda.
  auto screenstep = [&](int jc, const half8 (&A)[8]){
    f32x4 acc[4];
    #pragma unroll
    for(int h = 0; h < 4; h++) acc[h] = (f32x4){0.f,0.f,0.f,0.f};
    #pragma unroll
    for(int ks = 0; ks < 8; ks++){
      #pragma unroll
      for(int h = 0; h < 4; h++)
        acc[h] = __builtin_amdgcn_mfma_f32_16x16x32_f16(A[ks], bx[h][ks], acc[h], 0, 0, 0);
    }
    // D rows j = jc*64 + w*16 + 4q + r ; col i = i0 + h*16 + l15
    const int jbase = jc*64 + w*16 + 4*q;
    float4 xxv = *(const float4*)(&xxs[jbase]);
    float xr4[4] = {xxv.x, xxv.y, xxv.z, xxv.w};
    #pragma unroll
    for(int r = 0; r < 4; r++){
      #pragma unroll
      for(int h = 0; h < 4; h++){
        unsigned p = packkey(fmaf(2.0f, acc[h][r], -xr4[r]), jbase + r);
        // sorted insert via median: for a desc-sorted list,
        // min(old[k-1], max(old[k], p)) == median(old[k-1], old[k], p).
        #pragma unroll
        for(int k2 = 10; k2 >= 1; k2--){
          unsigned nk;
          asm("v_med3_u32 %0, %1, %2, %3"
              : "=v"(nk) : "v"(lst[h][k2-1]), "v"(lst[h][k2]), "v"(p));
          lst[h][k2] = nk;
        }
        {
          unsigned nk;
          asm("v_max_u32 %0, %1, %2"
              : "=v"(nk) : "v"(lst[h][0]), "v"(p));
          lst[h][0] = nk;
        }
      }
    }
  };

  // software pipeline: two static A-frag buffers, prefetch distance 1 (r3 shape).
  half8 A0[8], A1[8];
  {
    const ushort_t* pj = APTR(0);
    #pragma unroll
    for(int ks = 0; ks < 8; ks++) A0[ks] = *(const half8*)(pj + ks*32);
  }
  #pragma unroll 1
  for(int jc = 0; jc < 32; jc += 2){
    {
      const ushort_t* pj = APTR(jc + 1);
      #pragma unroll
      for(int ks = 0; ks < 8; ks++) A1[ks] = *(const half8*)(pj + ks*32);
    }
    screenstep(jc, A0);
    {
      const int jn = (jc + 2) & 31;   // wraps to 0 on last iter: harmless reload
      const ushort_t* pj = APTR(jn);
      #pragma unroll
      for(int ks = 0; ks < 8; ks++) A0[ks] = *(const half8*)(pj + ks*32);
    }
    screenstep(jc + 1, A1);
  }
  #undef APTR

  // dump: list h -> row (i0 + h*16 + l15), slot (w*4 + q), 11 packed words
  #pragma unroll
  for(int h = 0; h < 4; h++){
    size_t base = ((xb + i0 + h*16 + l15)*16 + (w*4 + q))*11;
    #pragma unroll
    for(int e = 0; e < 11; e++) knnP[base + e] = lst[h][e];
  }
}

// ---------------- K2b: merge 176 screen candidates/row + fp64 recheck ----------------
__global__ __launch_bounds__(256) void k_knnmerge(
    const unsigned* __restrict__ knnP, const float* __restrict__ xT,
    const double* __restrict__ xx, int* __restrict__ idxout){
  __shared__ unsigned Q[32][96];
  __shared__ int    mi[32][12];
  __shared__ double dk[32][12];
  __shared__ int    ambs[32];
  int b  = blockIdx.x;
  int i0 = blockIdx.y * 32;
  const size_t xb = (size_t)b * NN;
  int t = threadIdx.x;
  int r = t >> 3, s8 = t & 7;

  {
    unsigned loc[12];
    #pragma unroll
    for(int k2 = 0; k2 < 12; k2++) loc[k2] = 0u;
    const unsigned* src = knnP + ((xb + i0 + r)*16 + 2*s8)*11;
    #pragma unroll
    for(int e = 0; e < 22; e++){
      unsigned p = src[e];
      if(p > loc[11]){
        #pragma unroll
        for(int k2 = 0; k2 < 12; k2++){
          if(p > loc[k2]){ unsigned tv = loc[k2]; loc[k2] = p; p = tv; }
        }
      }
    }
    #pragma unroll
    for(int k2 = 0; k2 < 12; k2++) Q[r][s8*12 + k2] = loc[k2];
  }
  __syncthreads();
  if(t < 32){
    unsigned best[12];
    #pragma unroll
    for(int k2 = 0; k2 < 12; k2++) best[k2] = 0u;
    for(int e = 0; e < 96; e++){
      unsigned p = Q[t][e];
      if(p > best[11]){
        #pragma unroll
        for(int k2 = 0; k2 < 12; k2++){
          if(p > best[k2]){ unsigned tv = best[k2]; best[k2] = p; p = tv; }
        }
      }
    }
    float v9 = unpackval(best[9]), vA = unpackval(best[10]);
    int amb = (v9 - vA) <= (2.0f*DELTA);
    ambs[t] = amb;
    #pragma unroll
    for(int k2 = 0; k2 < 12; k2++) mi[t][k2] = (int)(best[k2] & 0x7FFu);
    if(!amb){
      size_t obase = ((size_t)b*NN + i0 + t)*KK;
      #pragma unroll
      for(int k2 = 0; k2 < 10; k2++) idxout[obase + k2] = mi[t][k2];
    }
  }
  __syncthreads();
  if(ambs[r]){
    const float* xip = xT + (xb + i0 + r)*CC;
    for(int e = s8; e < 12; e += 8){
      int jg = mi[r][e];
      const float* xjp = xT + (xb + jg)*CC;
      double s = 0.0;
      for(int c = 0; c < CC; c += 4){
        float4 a4 = *(const float4*)(xip + c);
        float4 b4 = *(const float4*)(xjp + c);
        s += (double)a4.x*b4.x + (double)a4.y*b4.y + (double)a4.z*b4.z + (double)a4.w*b4.w;
      }
      dk[r][e] = 2.0*s - xx[xb + jg];
    }
  }
  __syncthreads();
  if(t < 32 && ambs[t]){
    double bl[10]; int bi[10];
    #pragma unroll
    for(int k2 = 0; k2 < 10; k2++){ bl[k2] = -1e300; bi[k2] = 0x7fffffff; }
    for(int e = 0; e < 12; e++){
      double v = dk[t][e]; int j2 = mi[t][e];
      if(v > bl[9] || (v == bl[9] && j2 < bi[9])){
        double cv = v; int ci = j2;
        #pragma unroll
        for(int k2 = 0; k2 < 10; k2++){
          if(cv > bl[k2] || (cv == bl[k2] && ci < bi[k2])){
            double tv = bl[k2]; int ti = bi[k2]; bl[k2] = cv; bi[k2] = ci; cv = tv; ci = ti;
          }
        }
      }
    }
    size_t obase = ((size_t)b*NN + i0 + t)*KK;
    #pragma unroll
    for(int k2 = 0; k2 < 10; k2++) idxout[obase + k2] = bi[k2];
  }
}

// ---------------- K3: pointwise convs via MFMA: y1(fp16), y2(+sb1), t1=relu ----------------
// y1 stored fp16: it is ONLY consumed by k_s3max2's gather, whose result is
// packed to bf16 (coarser than fp16) before the U MFMA — error unchanged,
// gather traffic halved (168MB -> 84MB per dispatch).
__global__ __launch_bounds__(256) void k_pointwise(
    const ushort_t* __restrict__ xTh, const ushort_t* __restrict__ Wh,
    const float* __restrict__ Wc,
    ushort_t* __restrict__ y1h, float* __restrict__ y2t, float* __restrict__ t1t){
  const int b    = blockIdx.y;
  const int n0   = blockIdx.x * 64;
  const int t    = threadIdx.x;
  const int lane = t & 63, w = t >> 6;
  const int l15  = lane & 15, q = lane >> 4;
  const int wcol = w * 96;
  const ushort_t* pa = xTh + ((size_t)b*NN + n0 + l15)*CC + q*8;
  const ushort_t* pb = Wh + (size_t)(wcol + l15)*CC + q*8;
  f32x4 acc[4][6];
  #pragma unroll
  for(int mt = 0; mt < 4; mt++)
    #pragma unroll
    for(int nt = 0; nt < 6; nt++)
      acc[mt][nt] = (f32x4){0.f,0.f,0.f,0.f};
  #pragma unroll
  for(int ks = 0; ks < 8; ks++){
    half8 af[4], bf[6];
    #pragma unroll
    for(int mt = 0; mt < 4; mt++) af[mt] = *(const half8*)(pa + (size_t)mt*16*CC + ks*32);
    #pragma unroll
    for(int nt = 0; nt < 6; nt++) bf[nt] = *(const half8*)(pb + (size_t)nt*16*CC + ks*32);
    #pragma unroll
    for(int mt = 0; mt < 4; mt++)
      #pragma unroll
      for(int nt = 0; nt < 6; nt++)
        acc[mt][nt] = __builtin_amdgcn_mfma_f32_16x16x32_f16(af[mt], bf[nt], acc[mt][nt], 0, 0, 0);
  }
  // epilogue: D row = mt*16 + 4q + r (n), D col = wcol + nt*16 + l15 (o).
  // Each 16-wide nt-tile lies fully within one segment (boundaries 128/256
  // are multiples of 16) -> wave-uniform branch.
  #pragma unroll
  for(int nt = 0; nt < 6; nt++){
    int o = wcol + nt*16 + l15;
    if(o < 128){
      #pragma unroll
      for(int mt = 0; mt < 4; mt++){
        #pragma unroll
        for(int r = 0; r < 4; r++){
          int n = n0 + mt*16 + 4*q + r;
          _Float16 h = (_Float16)acc[mt][nt][r];
          y1h[((size_t)b*NN + n)*WW + o] = *reinterpret_cast<ushort_t*>(&h);
        }
      }
    } else if(o < 256){
      int oc = o - 128;
      float bias = Wc[SB1_O + oc];
      #pragma unroll
      for(int mt = 0; mt < 4; mt++){
        #pragma unroll
        for(int r = 0; r < 4; r++){
          int n = n0 + mt*16 + 4*q + r;
          y2t[((size_t)b*NN + n)*WW + oc] = acc[mt][nt][r] + bias;
        }
      }
    } else {
      int oc = o - 256;
      float bias = Wc[TB1_O + oc];
      #pragma unroll
      for(int mt = 0; mt < 4; mt++){
        #pragma unroll
        for(int r = 0; r < 4; r++){
          int n = n0 + mt*16 + 4*q + r;
          t1t[((size_t)b*NN + n)*WW + oc] = fmaxf(acc[mt][nt][r] + bias, 0.f);
        }
      }
    }
  }
}

// ---------------- K4: graph tail v3 — fp16 gather, single gather, 256-col MFMA ----------------
__global__ __launch_bounds__(256, 4) void k_s3max2(
    const ushort_t* __restrict__ y1h, const float* __restrict__ y2t,
    const int* __restrict__ idx, const float* __restrict__ Wc,
    const ushort_t* __restrict__ Wh3, float* __restrict__ soutT){
  __shared__ ushort_t Us[80][136];
  __shared__ float y2s[8][128];
  __shared__ int idxs[80];
  int b  = blockIdx.y;
  int n0 = blockIdx.x * 8;
  int t  = threadIdx.x;
  const int lane = t & 63, w = t >> 6, l15 = lane & 15, q = lane >> 4;

  if(t < 80) idxs[t] = idx[((size_t)b*NN + n0 + t/10)*KK + (t%10)];
  {
    int r = t >> 5, g = t & 31;
    *(float4*)&y2s[r][g*4] = *(const float4*)(y2t + ((size_t)b*NN + n0 + r)*WW + g*4);
  }
  const int g2 = t & 31;
  float4 w2r[4];
  #pragma unroll
  for(int e = 0; e < 4; e++) w2r[e] = *(const float4*)(Wc + SW2_O + (g2*4+e)*4);
  const float4 b2v = *(const float4*)(Wc + SB2_O + g2*4);
  __syncthreads();

  {
    int pr = t >> 5;
    #pragma unroll 2
    for(int it = 0; it < 10; it++){
      int p = it*8 + pr;
      int np = p / 10;
      int j = idxs[p];
      half4 yv = *(const half4*)(y1h + ((size_t)b*NN + j)*WW + g2*4);
      float4 y2v = *(const float4*)&y2s[np][g2*4];
      float v0 = fmaxf((float)yv[0] + y2v.x, 0.f);
      float v1 = fmaxf((float)yv[1] + y2v.y, 0.f);
      float v2 = fmaxf((float)yv[2] + y2v.z, 0.f);
      float v3 = fmaxf((float)yv[3] + y2v.w, 0.f);
      float4 u;
      u.x = fmaxf(b2v.x + w2r[0].x*v0 + w2r[0].y*v1 + w2r[0].z*v2 + w2r[0].w*v3, 0.f);
      u.y = fmaxf(b2v.y + w2r[1].x*v0 + w2r[1].y*v1 + w2r[1].z*v2 + w2r[1].w*v3, 0.f);
      u.z = fmaxf(b2v.z + w2r[2].x*v0 + w2r[2].y*v1 + w2r[2].z*v2 + w2r[2].w*v3, 0.f);
      u.w = fmaxf(b2v.w + w2r[3].x*v0 + w2r[3].y*v1 + w2r[3].z*v2 + w2r[3].w*v3, 0.f);
      *(uint2*)&Us[p][g2*4] = f4_to_bf4(u);
    }
  }
  __syncthreads();

  // MFMA: wave w covers output cols w*64 .. w*64+63 in 4 tiles of 16
  #pragma unroll
  for(int nt = 0; nt < 4; nt++){
    const int col = w*64 + nt*16 + l15;
    short8 bf[4];
    #pragma unroll
    for(int k = 0; k < 4; k++)
      bf[k] = *(const short8*)(Wh3 + (size_t)col*WW + k*32 + q*8);
    f32x4 a5[5];
    #pragma unroll
    for(int mt = 0; mt < 5; mt++) a5[mt] = (f32x4){0.f,0.f,0.f,0.f};
    #pragma unroll
    for(int k = 0; k < 4; k++){
      #pragma unroll
      for(int mt = 0; mt < 5; mt++){
        short8 af = *(const short8*)(&Us[mt*16 + l15][k*32 + q*8]);
        a5[mt] = __builtin_amdgcn_mfma_f32_16x16x32_bf16(af, bf[k], a5[mt], 0, 0, 0);
      }
    }
    // D rows = mt*16 + 4q + r (p index), col = col. max over groups of 10 rows.
    float gm[8];
    #pragma unroll
    for(int g = 0; g < 8; g++) gm[g] = -3e38f;
    if(q == 0){
      gm[0]=max4(a5[0]); gm[1]=max4(a5[1]); gm[3]=max4(a5[2]);
      gm[4]=fmaxf(a5[3][0],a5[3][1]); gm[5]=fmaxf(a5[3][2],a5[3][3]); gm[6]=max4(a5[4]);
    } else if(q == 1){
      gm[0]=max4(a5[0]); gm[2]=max4(a5[1]); gm[3]=max4(a5[2]); gm[5]=max4(a5[3]);
      gm[6]=fmaxf(a5[4][0],a5[4][1]); gm[7]=fmaxf(a5[4][2],a5[4][3]);
    } else if(q == 2){
      gm[0]=fmaxf(a5[0][0],a5[0][1]); gm[1]=fmaxf(a5[0][2],a5[0][3]);
      gm[2]=max4(a5[1]); gm[4]=max4(a5[2]); gm[5]=max4(a5[3]); gm[7]=max4(a5[4]);
    } else {
      gm[1]=max4(a5[0]); gm[2]=fmaxf(a5[1][0],a5[1][1]); gm[3]=fmaxf(a5[1][2],a5[1][3]);
      gm[4]=max4(a5[2]); gm[6]=max4(a5[3]); gm[7]=max4(a5[4]);
    }
    #pragma unroll
    for(int g = 0; g < 8; g++){
      float v = gm[g];
      v = fmaxf(v, __shfl_xor(v, 16));
      v = fmaxf(v, __shfl_xor(v, 32));
      gm[g] = v;
    }
    float bias = Wc[SB3_O + col];
    soutT[((size_t)b*NN + n0 + 2*q)*CC + col]     = gm[2*q] + bias;
    soutT[((size_t)b*NN + n0 + 2*q + 1)*CC + col] = gm[2*q+1] + bias;
  }
}

// ---------------- K5: temporal tail v3 — conv3 + fp16 MFMA GEMM + FUSED final ----------------
__global__ __launch_bounds__(256, 4) void k_tout(
    const float* __restrict__ t1t, const float* __restrict__ Wc,
    const ushort_t* __restrict__ Wh3t, const float* __restrict__ soutT,
    const void* __restrict__ xraw, void* __restrict__ outraw){
  __shared__ ushort_t t2s[32][136];
  int b  = blockIdx.y;
  int n0 = blockIdx.x * 32;
  int t  = threadIdx.x;
  const int lane = t & 63, w = t >> 6, l15 = lane & 15, q = lane >> 4;
  const int isf = detect_isf(xraw, lane);
  // phase 1: grouped conv3 (each thread: one o-channel, 16 rows)
  {
    int o = t & 127;
    int rbase = t >> 7;   // 0 or 1
    float w2v[12];
    #pragma unroll
    for(int z = 0; z < 12; z++) w2v[z] = Wc[TW2_O + o*12 + z];
    float bv = Wc[TB2_O + o];
    int ob = o & ~3;
    for(int e = 0; e < 16; e++){
      int r = rbase + 2*e;
      int n = n0 + r;
      float acc = bv;
      #pragma unroll
      for(int d = 0; d < 3; d++){
        int nn2 = n + d - 1;
        if(nn2 >= 0 && nn2 < NN){
          float4 tv = *(const float4*)(t1t + ((size_t)b*NN + nn2)*WW + ob);
          acc += w2v[0*3+d]*tv.x + w2v[1*3+d]*tv.y + w2v[2*3+d]*tv.z + w2v[3*3+d]*tv.w;
        }
      }
      float vr = fmaxf(acc, 0.f);
      _Float16 h = (_Float16)vr;
      t2s[r][o] = *reinterpret_cast<ushort_t*>(&h);
    }
  }
  __syncthreads();
  // phase 2: MFMA 32x256x128; wave w -> cols w*64 .. w*64+63 (4 nt-tiles of 16)
  #pragma unroll
  for(int nt = 0; nt < 4; nt++){
    const int col = w*64 + nt*16 + l15;
    half8 bf[4];
    #pragma unroll
    for(int k = 0; k < 4; k++)
      bf[k] = *(const half8*)(Wh3t + (size_t)col*WW + k*32 + q*8);
    f32x4 acc[2];
    acc[0] = (f32x4){0.f,0.f,0.f,0.f};
    acc[1] = (f32x4){0.f,0.f,0.f,0.f};
    #pragma unroll
    for(int k = 0; k < 4; k++){
      #pragma unroll
      for(int mt = 0; mt < 2; mt++){
        half8 af = *(const half8*)(&t2s[mt*16 + l15][k*32 + q*8]);
        acc[mt] = __builtin_amdgcn_mfma_f32_16x16x32_f16(af, bf[k], acc[mt], 0, 0, 0);
      }
    }
    // D row = mt*16 + 4q + r (n), col = col. Fused final:
    // out[(b*CC+col)*NN + n] = relu(soutT[(b*NN+n)*CC+col] + acc + tb3 + x[...])
    float bias = Wc[TB3_O + col];
    #pragma unroll
    for(int mt = 0; mt < 2; mt++){
      int nbase = n0 + mt*16 + 4*q;                 // 4 consecutive n (r=0..3)
      size_t xoff = ((size_t)b*CC + col)*NN + nbase;
      float xv[4];
      if(isf){
        float4 x4 = *(const float4*)((const float*)xraw + xoff);
        xv[0]=x4.x; xv[1]=x4.y; xv[2]=x4.z; xv[3]=x4.w;
      } else {
        const ushort_t* xh = (const ushort_t*)xraw + xoff;
        #pragma unroll
        for(int r = 0; r < 4; r++) xv[r] = bfs(xh[r]);
      }
      float4 v4;
      #pragma unroll
      for(int r = 0; r < 4; r++){
        int n = nbase + r;
        float sv = soutT[((size_t)b*NN + n)*CC + col];
        float comb = sv + acc[mt][r] + bias;
        ((float*)&v4)[r] = fmaxf(comb + xv[r], 0.f);
      }
      if(isf){
        *(float4*)((float*)outraw + xoff) = v4;
      } else {
        *(uint2*)((ushort_t*)outraw + xoff) = f4_to_bf4(v4);
      }
    }
  }
}

extern "C" void kernel_launch(void* const* d_in, const int* in_sizes, int n_in,
                              void* d_out, int out_size, void* d_ws, size_t ws_size,
                              hipStream_t stream){
  char* ws = (char*)d_ws;
  // workspace layout (bytes)
  float*    Wc    = (float*)   (ws + 256);          //    667,648
  float*    xT    = (float*)   (ws + 1048576);      // 33,554,432
  double*   xx    = (double*)  (ws + 34603008);     //    262,144
  float*    xxf   = (float*)   (ws + 34865152);     //    131,072
  int*      idx   = (int*)     (ws + 34996224);     //  1,310,720
  ushort_t* y1h   = (ushort_t*)(ws + 36306944);     //  8,388,608 (fp16, in old y1t slot)
  float*    y2t   = (float*)   (ws + 53084160);     // 16,777,216
  float*    t1t   = (float*)   (ws + 69861376);     // 16,777,216
  float*    soutT = (float*)   (ws + 86638592);     // 33,554,432
  ushort_t* xTh   = (ushort_t*)(ws + 120193024);    // 16,777,216
  unsigned* knnP  = (unsigned*)(ws + 136970240);    // 23,068,672  (end 160,038,912)
  // Wh (fp16 384x256) + Wh3 (bf16 256x128) + Wh3t (fp16 256x128) reuse the knnP
  // region (dead after k_knnmerge).
  ushort_t* Wh    = (ushort_t*)(ws + 136970240);    //    196,608
  ushort_t* Wh3   = (ushort_t*)(ws + 137166848);    //     65,536
  ushort_t* Wh3t  = (ushort_t*)(ws + 137232384);    //     65,536

  k_convw<<<dim3(64,12), 256, 0, stream>>>(d_in[0],
                                           d_in[1], d_in[2], d_in[3], d_in[4], d_in[5], d_in[6],
                                           d_in[7], d_in[8], d_in[9], d_in[10], d_in[11], d_in[12],
                                           Wc);
  k_convx<<<dim3(64,8,16), dim3(32,8), 0, stream>>>(d_in[0], xT, xTh);
  k_norms<<<dim3(8192), dim3(256), 0, stream>>>(xT, xx, xxf);
  k_knn<<<dim3(16,32), dim3(256), 0, stream>>>(xTh, xxf, knnP);
  k_knnmerge<<<dim3(16,64), dim3(256), 0, stream>>>(knnP, xT, xx, idx);
  k_convwh<<<dim3(640), 256, 0, stream>>>(Wc, Wh, Wh3, Wh3t);
  k_pointwise<<<dim3(32,16), 256, 0, stream>>>(xTh, Wh, Wc, y1h, y2t, t1t);
  k_s3max2<<<dim3(256,16), dim3(256), 0, stream>>>(y1h, y2t, idx, Wc, Wh3, soutT);
  k_tout<<<dim3(64,16), dim3(256), 0, stream>>>(t1t, Wc, Wh3t, soutT, d_in[0], d_out);
}

// Round 19
// 343.299 us; speedup vs baseline: 1.1178x; 1.1178x over previous
//
#include <hip/hip_runtime.h>
#include <hip/hip_bf16.h>
#include <stdint.h>

#define BB 16
#define CC 256
#define NN 2048
#define KK 10
#define WW 128
#define DELTA 0.10f

typedef unsigned short ushort_t;
typedef __attribute__((ext_vector_type(8))) _Float16 half8;
typedef __attribute__((ext_vector_type(4))) _Float16 half4;
typedef __attribute__((ext_vector_type(8))) short short8;
typedef __attribute__((ext_vector_type(4))) float f32x4;

// converted-weight table offsets (fp32 elements)
#define TW1_O 0
#define TB1_O 32768
#define TW2_O 32896
#define TB2_O 34432
#define TW3_O 34560
#define TB3_O 67328
#define SW1_O 67584
#define SB1_O 133120
#define SW2_O 133248
#define SB2_O 133760
#define SW3_O 133888
#define SB3_O 166656

__device__ __forceinline__ float bflo(unsigned p){ union{unsigned u; float f;} v; v.u = p << 16; return v.f; }
__device__ __forceinline__ float bfhi(unsigned p){ union{unsigned u; float f;} v; v.u = p & 0xffff0000u; return v.f; }
__device__ __forceinline__ float bfs(ushort_t u){ union{unsigned u; float f;} v; v.u = ((unsigned)u) << 16; return v.f; }
__device__ __forceinline__ ushort_t f2bf16(float f){
  __hip_bfloat16 h = __float2bfloat16(f);
  return *reinterpret_cast<ushort_t*>(&h);
}
__device__ __forceinline__ uint2 f4_to_bf4(float4 v){
  uint2 r;
  r.x = (unsigned)f2bf16(v.x) | ((unsigned)f2bf16(v.y) << 16);
  r.y = (unsigned)f2bf16(v.z) | ((unsigned)f2bf16(v.w) << 16);
  return r;
}
__device__ __forceinline__ float max4(f32x4 v){ return fmaxf(fmaxf(v[0],v[1]), fmaxf(v[2],v[3])); }

// packed screen key: sortable-uint(value) high 21 bits | j-index low 11 bits
__device__ __forceinline__ unsigned packkey(float k, int j){
  unsigned u = __float_as_uint(k);
  unsigned s = u ^ (unsigned)(((int)u >> 31) | (int)0x80000000);
  return (s & 0xFFFFF800u) | (unsigned)j;
}
__device__ __forceinline__ float unpackval(unsigned p){
  unsigned s = p & 0xFFFFF800u;
  unsigned u = (s & 0x80000000u) ? (s & 0x7FFFFFFFu) : ~s;
  return __uint_as_float(u);
}

// wave-parallel input-dtype probe: fp32 data read as bf16 pairs -> garbage exponents.
__device__ __forceinline__ int detect_isf(const void* xraw, int lane){
  unsigned u = ((const unsigned*)xraw)[lane];
  float a = fabsf(bflo(u)), c = fabsf(bfhi(u));
  if(!(a < 1e30f)) a = 1e30f;
  if(!(c < 1e30f)) c = 1e30f;
  float m = fmaxf(a, c);
  #pragma unroll
  for(int off = 32; off > 0; off >>= 1) m = fmaxf(m, __shfl_xor(m, off));
  return m > 1e3f;   // 1 => inputs are fp32
}

// ---------------- D1: convert all weights/biases to fp32 table ----------------
__global__ void k_convw(const void* xraw,
                        const void* p0, const void* p1, const void* p2, const void* p3,
                        const void* p4, const void* p5, const void* p6, const void* p7,
                        const void* p8, const void* p9, const void* p10, const void* p11,
                        float* __restrict__ dst){
  const int counts[12] = {32768,128,1536,128,32768,256,65536,128,512,128,32768,256};
  const int offs[12]   = {TW1_O,TB1_O,TW2_O,TB2_O,TW3_O,TB3_O,SW1_O,SB1_O,SW2_O,SB2_O,SW3_O,SB3_O};
  int a = blockIdx.y;
  const void* src;
  switch(a){
    case 0: src=p0; break; case 1: src=p1; break; case 2: src=p2; break;
    case 3: src=p3; break; case 4: src=p4; break; case 5: src=p5; break;
    case 6: src=p6; break; case 7: src=p7; break; case 8: src=p8; break;
    case 9: src=p9; break; case 10: src=p10; break; default: src=p11; break;
  }
  int isf = detect_isf(xraw, threadIdx.x & 63);
  int cnt = counts[a], off = offs[a];
  for(int i = blockIdx.x*256 + threadIdx.x; i < cnt; i += gridDim.x*256){
    float v = isf ? ((const float*)src)[i] : bfs(((const ushort_t*)src)[i]);
    dst[off + i] = v;
  }
}

// ---------------- D1b: pack {sw1_nbr, sw1_ctr, tw1} fp16 + sw3 bf16 + tw3 fp16 ----------------
__global__ void k_convwh(const float* __restrict__ Wc, ushort_t* __restrict__ Wh,
                         ushort_t* __restrict__ Wh3, ushort_t* __restrict__ Wh3t){
  int o = blockIdx.x;
  int t = threadIdx.x;   // 0..255
  if(o < 384){
    float v;
    if(o < 128)      v = Wc[SW1_O + o*512 + t];            // sw1 neighbor part
    else if(o < 256) v = Wc[SW1_O + (o-128)*512 + 256 + t];// sw1 center part
    else             v = Wc[TW1_O + (o-256)*256 + t];      // tw1
    _Float16 h = (_Float16)v;
    Wh[(size_t)o*CC + t] = *reinterpret_cast<ushort_t*>(&h);
  } else if(o < 512){
    // sw3 (256 x 128, row-major) -> bf16, linear copy
    int i = (o - 384)*256 + t;   // 0..32767
    Wh3[i] = f2bf16(Wc[SW3_O + i]);
  } else {
    // tw3 (256 x 128, row-major) -> fp16, linear copy
    int i = (o - 512)*256 + t;   // 0..32767
    _Float16 h = (_Float16)Wc[TW3_O + i];
    Wh3t[i] = *reinterpret_cast<ushort_t*>(&h);
  }
}

// ---------------- D2: canonicalize x -> xT fp32 (B,N,C) + fp16 copy ----------------
__global__ void k_convx(const void* __restrict__ xraw,
                        float* __restrict__ xT, ushort_t* __restrict__ xTh){
  __shared__ float tile[32][33];
  int tx = threadIdx.x, ty = threadIdx.y;
  int isf = detect_isf(xraw, (ty*32 + tx) & 63);
  int b = blockIdx.z;
  int n0 = blockIdx.x * 32;
  int c0 = blockIdx.y * 32;
  #pragma unroll
  for(int r = 0; r < 4; r++){
    int c = c0 + ty + r*8;
    size_t off = ((size_t)b*CC + c)*NN + n0 + tx;
    float v = isf ? ((const float*)xraw)[off] : bfs(((const ushort_t*)xraw)[off]);
    tile[ty + r*8][tx] = v;
  }
  __syncthreads();
  #pragma unroll
  for(int r = 0; r < 4; r++){
    int n = n0 + ty + r*8;
    size_t off = ((size_t)b*NN + n)*CC + c0 + tx;
    float v = tile[tx][ty + r*8];
    xT[off] = v;
    _Float16 h = (_Float16)v;
    xTh[off] = *reinterpret_cast<ushort_t*>(&h);
  }
}

// ---------------- K1: row norms (fp64 + fp32 copy) ----------------
__global__ void k_norms(const float* __restrict__ xT, double* __restrict__ xx,
                        float* __restrict__ xxf){
  int row = blockIdx.x*4 + (threadIdx.x >> 6);
  int lane = threadIdx.x & 63;
  float4 q = *(const float4*)(xT + (size_t)row*CC + lane*4);
  double s = (double)q.x*q.x + (double)q.y*q.y + (double)q.z*q.z + (double)q.w*q.w;
  #pragma unroll
  for(int off = 32; off > 0; off >>= 1) s += __shfl_down(s, off);
  if(lane == 0){ xx[row] = s; xxf[row] = (float)s; }
}

// ---------------- K2: kNN screen v13 — fused screen + in-block merge + recheck ----------------
// grid (B, N/64); block 256 (4 waves), 2 blocks/CU. Main loop = r14-verified
// 64-i + med3 + dbuf structure (unchanged). NEW: all 16 slots of each row live
// in THIS block (slot = w*4+q), so the merge is done in-block via LDS instead
// of round-tripping 23MB of packed lists through global (k_knnmerge deleted).
// Merge semantics bit-identical: top-12-of-union == top-12-of(top-12-of-parts)
// for any slot partition (keys unique: j-index in low bits); gap check + fp64
// recheck copied verbatim. LDS: 8K xxs + 45K Q2 + 12K QM + 9.5K misc = 75KB ->
// 2 blocks/CU (unchanged occupancy).
__global__ __launch_bounds__(256, 2) void k_knn(
    const ushort_t* __restrict__ xTh, const float* __restrict__ xxf,
    const float* __restrict__ xT, const double* __restrict__ xx,
    int* __restrict__ idxout){
  __shared__ float xxs[2048];
  __shared__ unsigned Q2[64][176];   // [row][slot*11 + e]
  __shared__ unsigned QM[64][48];
  __shared__ int    mi_s[64][12];
  __shared__ double dk_s[64][12];
  __shared__ int    ambs_s[64];
  const int t    = threadIdx.x;
  const int lane = t & 63;
  const int w    = t >> 6;
  const int b    = blockIdx.x;
  const int i0   = blockIdx.y * 64;
  const size_t xb = (size_t)b * NN;
  const int l15  = lane & 15;
  const int q    = lane >> 4;

  // stage shifted norms (key = 2*dot - (xx - 256): shrinks |key| for packing)
  for(int e = t; e < 2048; e += 256) xxs[e] = xxf[xb + e] - 256.0f;

  // B-frags: xi rows i0..i0+63 (four 16-row halves), fp16, K=256: 128 regs
  half8 bx[4][8];
  #pragma unroll
  for(int h = 0; h < 4; h++){
    const ushort_t* pi = xTh + (xb + i0 + h*16 + l15)*CC + q*8;
    #pragma unroll
    for(int ks = 0; ks < 8; ks++) bx[h][ks] = *(const half8*)(pi + ks*32);
  }

  unsigned lst[4][11];
  #pragma unroll
  for(int h = 0; h < 4; h++)
    #pragma unroll
    for(int k2 = 0; k2 < 11; k2++) lst[h][k2] = 0u;

  __syncthreads();

  const int arow = w*16 + l15;        // this lane's A-frag row within a jc-tile
  #define APTR(JC) (xTh + (xb + (size_t)(JC)*64 + arow)*CC + q*8)

  // MFMA + med3 screen for one jc-tile; acc strictly local to this lambda
  // (r8/r9 miscompile had acc in outer scope shared between lambdas).
  auto screenstep = [&](int jc, const half8 (&A)[8]){
    f32x4 acc[4];
    #pragma unroll
    for(int h = 0; h < 4; h++) acc[h] = (f32x4){0.f,0.f,0.f,0.f};
    #pragma unroll
    for(int ks = 0; ks < 8; ks++){
      #pragma unroll
      for(int h = 0; h < 4; h++)
        acc[h] = __builtin_amdgcn_mfma_f32_16x16x32_f16(A[ks], bx[h][ks], acc[h], 0, 0, 0);
    }
    // D rows j = jc*64 + w*16 + 4q + r ; col i = i0 + h*16 + l15
    const int jbase = jc*64 + w*16 + 4*q;
    float4 xxv = *(const float4*)(&xxs[jbase]);
    float xr4[4] = {xxv.x, xxv.y, xxv.z, xxv.w};
    #pragma unroll
    for(int r = 0; r < 4; r++){
      #pragma unroll
      for(int h = 0; h < 4; h++){
        unsigned p = packkey(fmaf(2.0f, acc[h][r], -xr4[r]), jbase + r);
        // sorted insert via median: desc-sorted list,
        // min(old[k-1], max(old[k], p)) == median(old[k-1], old[k], p).
        #pragma unroll
        for(int k2 = 10; k2 >= 1; k2--){
          unsigned nk;
          asm("v_med3_u32 %0, %1, %2, %3"
              : "=v"(nk) : "v"(lst[h][k2-1]), "v"(lst[h][k2]), "v"(p));
          lst[h][k2] = nk;
        }
        {
          unsigned nk;
          asm("v_max_u32 %0, %1, %2"
              : "=v"(nk) : "v"(lst[h][0]), "v"(p));
          lst[h][0] = nk;
        }
      }
    }
  };

  // software pipeline: two static A-frag buffers, prefetch distance 1 (r3 shape).
  half8 A0[8], A1[8];
  {
    const ushort_t* pj = APTR(0);
    #pragma unroll
    for(int ks = 0; ks < 8; ks++) A0[ks] = *(const half8*)(pj + ks*32);
  }
  #pragma unroll 1
  for(int jc = 0; jc < 32; jc += 2){
    {
      const ushort_t* pj = APTR(jc + 1);
      #pragma unroll
      for(int ks = 0; ks < 8; ks++) A1[ks] = *(const half8*)(pj + ks*32);
    }
    screenstep(jc, A0);
    {
      const int jn = (jc + 2) & 31;   // wraps to 0 on last iter: harmless reload
      const ushort_t* pj = APTR(jn);
      #pragma unroll
      for(int ks = 0; ks < 8; ks++) A0[ks] = *(const half8*)(pj + ks*32);
    }
    screenstep(jc + 1, A1);
  }
  #undef APTR

  // dump lists to LDS: row_local = h*16 + l15, slot = w*4 + q
  #pragma unroll
  for(int h = 0; h < 4; h++){
    unsigned* dst = &Q2[h*16 + l15][(w*4 + q)*11];
    #pragma unroll
    for(int e = 0; e < 11; e++) dst[e] = lst[h][e];
  }
  __syncthreads();

  // merge stage 1: 4 threads/row; thread merges 4 slots (44 entries) -> top-12
  {
    int r = t >> 2, s4 = t & 3;
    unsigned loc[12];
    #pragma unroll
    for(int k2 = 0; k2 < 12; k2++) loc[k2] = 0u;
    const unsigned* src = &Q2[r][s4*44];
    #pragma unroll
    for(int e = 0; e < 44; e++){
      unsigned p = src[e];
      if(p > loc[11]){
        #pragma unroll
        for(int k2 = 0; k2 < 12; k2++){
          if(p > loc[k2]){ unsigned tv = loc[k2]; loc[k2] = p; p = tv; }
        }
      }
    }
    #pragma unroll
    for(int k2 = 0; k2 < 12; k2++) QM[r][s4*12 + k2] = loc[k2];
  }
  __syncthreads();
  // merge stage 2: thread t<64 -> row t; merge 48 -> top-12, gap check
  if(t < 64){
    unsigned best[12];
    #pragma unroll
    for(int k2 = 0; k2 < 12; k2++) best[k2] = 0u;
    for(int e = 0; e < 48; e++){
      unsigned p = QM[t][e];
      if(p > best[11]){
        #pragma unroll
        for(int k2 = 0; k2 < 12; k2++){
          if(p > best[k2]){ unsigned tv = best[k2]; best[k2] = p; p = tv; }
        }
      }
    }
    float v9 = unpackval(best[9]), vA = unpackval(best[10]);
    int amb = (v9 - vA) <= (2.0f*DELTA);
    ambs_s[t] = amb;
    #pragma unroll
    for(int k2 = 0; k2 < 12; k2++) mi_s[t][k2] = (int)(best[k2] & 0x7FFu);
    if(!amb){
      size_t obase = ((size_t)b*NN + i0 + t)*KK;
      #pragma unroll
      for(int k2 = 0; k2 < 10; k2++) idxout[obase + k2] = mi_s[t][k2];
    }
  }
  __syncthreads();
  // fp64 recheck for ambiguous rows: 4 threads/row, 3 candidates each
  {
    int r = t >> 2, s4 = t & 3;
    if(ambs_s[r]){
      const float* xip = xT + (xb + i0 + r)*CC;
      for(int e = s4; e < 12; e += 4){
        int jg = mi_s[r][e];
        const float* xjp = xT + (xb + jg)*CC;
        double s = 0.0;
        for(int c = 0; c < CC; c += 4){
          float4 a4 = *(const float4*)(xip + c);
          float4 b4 = *(const float4*)(xjp + c);
          s += (double)a4.x*b4.x + (double)a4.y*b4.y + (double)a4.z*b4.z + (double)a4.w*b4.w;
        }
        dk_s[r][e] = 2.0*s - xx[xb + jg];
      }
    }
  }
  __syncthreads();
  if(t < 64 && ambs_s[t]){
    double bl[10]; int bi[10];
    #pragma unroll
    for(int k2 = 0; k2 < 10; k2++){ bl[k2] = -1e300; bi[k2] = 0x7fffffff; }
    for(int e = 0; e < 12; e++){
      double v = dk_s[t][e]; int j2 = mi_s[t][e];
      if(v > bl[9] || (v == bl[9] && j2 < bi[9])){
        double cv = v; int ci = j2;
        #pragma unroll
        for(int k2 = 0; k2 < 10; k2++){
          if(cv > bl[k2] || (cv == bl[k2] && ci < bi[k2])){
            double tv = bl[k2]; int ti = bi[k2]; bl[k2] = cv; bi[k2] = ci; cv = tv; ci = ti;
          }
        }
      }
    }
    size_t obase = ((size_t)b*NN + i0 + t)*KK;
    #pragma unroll
    for(int k2 = 0; k2 < 10; k2++) idxout[obase + k2] = bi[k2];
  }
}

// ---------------- K3: pointwise convs via MFMA: y1(fp16), y2(+sb1), t1=relu ----------------
__global__ __launch_bounds__(256) void k_pointwise(
    const ushort_t* __restrict__ xTh, const ushort_t* __restrict__ Wh,
    const float* __restrict__ Wc,
    ushort_t* __restrict__ y1h, float* __restrict__ y2t, float* __restrict__ t1t){
  const int b    = blockIdx.y;
  const int n0   = blockIdx.x * 64;
  const int t    = threadIdx.x;
  const int lane = t & 63, w = t >> 6;
  const int l15  = lane & 15, q = lane >> 4;
  const int wcol = w * 96;
  const ushort_t* pa = xTh + ((size_t)b*NN + n0 + l15)*CC + q*8;
  const ushort_t* pb = Wh + (size_t)(wcol + l15)*CC + q*8;
  f32x4 acc[4][6];
  #pragma unroll
  for(int mt = 0; mt < 4; mt++)
    #pragma unroll
    for(int nt = 0; nt < 6; nt++)
      acc[mt][nt] = (f32x4){0.f,0.f,0.f,0.f};
  #pragma unroll
  for(int ks = 0; ks < 8; ks++){
    half8 af[4], bf[6];
    #pragma unroll
    for(int mt = 0; mt < 4; mt++) af[mt] = *(const half8*)(pa + (size_t)mt*16*CC + ks*32);
    #pragma unroll
    for(int nt = 0; nt < 6; nt++) bf[nt] = *(const half8*)(pb + (size_t)nt*16*CC + ks*32);
    #pragma unroll
    for(int mt = 0; mt < 4; mt++)
      #pragma unroll
      for(int nt = 0; nt < 6; nt++)
        acc[mt][nt] = __builtin_amdgcn_mfma_f32_16x16x32_f16(af[mt], bf[nt], acc[mt][nt], 0, 0, 0);
  }
  #pragma unroll
  for(int nt = 0; nt < 6; nt++){
    int o = wcol + nt*16 + l15;
    if(o < 128){
      #pragma unroll
      for(int mt = 0; mt < 4; mt++){
        #pragma unroll
        for(int r = 0; r < 4; r++){
          int n = n0 + mt*16 + 4*q + r;
          _Float16 h = (_Float16)acc[mt][nt][r];
          y1h[((size_t)b*NN + n)*WW + o] = *reinterpret_cast<ushort_t*>(&h);
        }
      }
    } else if(o < 256){
      int oc = o - 128;
      float bias = Wc[SB1_O + oc];
      #pragma unroll
      for(int mt = 0; mt < 4; mt++){
        #pragma unroll
        for(int r = 0; r < 4; r++){
          int n = n0 + mt*16 + 4*q + r;
          y2t[((size_t)b*NN + n)*WW + oc] = acc[mt][nt][r] + bias;
        }
      }
    } else {
      int oc = o - 256;
      float bias = Wc[TB1_O + oc];
      #pragma unroll
      for(int mt = 0; mt < 4; mt++){
        #pragma unroll
        for(int r = 0; r < 4; r++){
          int n = n0 + mt*16 + 4*q + r;
          t1t[((size_t)b*NN + n)*WW + oc] = fmaxf(acc[mt][nt][r] + bias, 0.f);
        }
      }
    }
  }
}

// ---------------- K4: graph tail v3 — fp16 gather, single gather, 256-col MFMA ----------------
__global__ __launch_bounds__(256, 4) void k_s3max2(
    const ushort_t* __restrict__ y1h, const float* __restrict__ y2t,
    const int* __restrict__ idx, const float* __restrict__ Wc,
    const ushort_t* __restrict__ Wh3, float* __restrict__ soutT){
  __shared__ ushort_t Us[80][136];
  __shared__ float y2s[8][128];
  __shared__ int idxs[80];
  int b  = blockIdx.y;
  int n0 = blockIdx.x * 8;
  int t  = threadIdx.x;
  const int lane = t & 63, w = t >> 6, l15 = lane & 15, q = lane >> 4;

  if(t < 80) idxs[t] = idx[((size_t)b*NN + n0 + t/10)*KK + (t%10)];
  {
    int r = t >> 5, g = t & 31;
    *(float4*)&y2s[r][g*4] = *(const float4*)(y2t + ((size_t)b*NN + n0 + r)*WW + g*4);
  }
  const int g2 = t & 31;
  float4 w2r[4];
  #pragma unroll
  for(int e = 0; e < 4; e++) w2r[e] = *(const float4*)(Wc + SW2_O + (g2*4+e)*4);
  const float4 b2v = *(const float4*)(Wc + SB2_O + g2*4);
  __syncthreads();

  {
    int pr = t >> 5;
    #pragma unroll 2
    for(int it = 0; it < 10; it++){
      int p = it*8 + pr;
      int np = p / 10;
      int j = idxs[p];
      half4 yv = *(const half4*)(y1h + ((size_t)b*NN + j)*WW + g2*4);
      float4 y2v = *(const float4*)&y2s[np][g2*4];
      float v0 = fmaxf((float)yv[0] + y2v.x, 0.f);
      float v1 = fmaxf((float)yv[1] + y2v.y, 0.f);
      float v2 = fmaxf((float)yv[2] + y2v.z, 0.f);
      float v3 = fmaxf((float)yv[3] + y2v.w, 0.f);
      float4 u;
      u.x = fmaxf(b2v.x + w2r[0].x*v0 + w2r[0].y*v1 + w2r[0].z*v2 + w2r[0].w*v3, 0.f);
      u.y = fmaxf(b2v.y + w2r[1].x*v0 + w2r[1].y*v1 + w2r[1].z*v2 + w2r[1].w*v3, 0.f);
      u.z = fmaxf(b2v.z + w2r[2].x*v0 + w2r[2].y*v1 + w2r[2].z*v2 + w2r[2].w*v3, 0.f);
      u.w = fmaxf(b2v.w + w2r[3].x*v0 + w2r[3].y*v1 + w2r[3].z*v2 + w2r[3].w*v3, 0.f);
      *(uint2*)&Us[p][g2*4] = f4_to_bf4(u);
    }
  }
  __syncthreads();

  #pragma unroll
  for(int nt = 0; nt < 4; nt++){
    const int col = w*64 + nt*16 + l15;
    short8 bf[4];
    #pragma unroll
    for(int k = 0; k < 4; k++)
      bf[k] = *(const short8*)(Wh3 + (size_t)col*WW + k*32 + q*8);
    f32x4 a5[5];
    #pragma unroll
    for(int mt = 0; mt < 5; mt++) a5[mt] = (f32x4){0.f,0.f,0.f,0.f};
    #pragma unroll
    for(int k = 0; k < 4; k++){
      #pragma unroll
      for(int mt = 0; mt < 5; mt++){
        short8 af = *(const short8*)(&Us[mt*16 + l15][k*32 + q*8]);
        a5[mt] = __builtin_amdgcn_mfma_f32_16x16x32_bf16(af, bf[k], a5[mt], 0, 0, 0);
      }
    }
    float gm[8];
    #pragma unroll
    for(int g = 0; g < 8; g++) gm[g] = -3e38f;
    if(q == 0){
      gm[0]=max4(a5[0]); gm[1]=max4(a5[1]); gm[3]=max4(a5[2]);
      gm[4]=fmaxf(a5[3][0],a5[3][1]); gm[5]=fmaxf(a5[3][2],a5[3][3]); gm[6]=max4(a5[4]);
    } else if(q == 1){
      gm[0]=max4(a5[0]); gm[2]=max4(a5[1]); gm[3]=max4(a5[2]); gm[5]=max4(a5[3]);
      gm[6]=fmaxf(a5[4][0],a5[4][1]); gm[7]=fmaxf(a5[4][2],a5[4][3]);
    } else if(q == 2){
      gm[0]=fmaxf(a5[0][0],a5[0][1]); gm[1]=fmaxf(a5[0][2],a5[0][3]);
      gm[2]=max4(a5[1]); gm[4]=max4(a5[2]); gm[5]=max4(a5[3]); gm[7]=max4(a5[4]);
    } else {
      gm[1]=max4(a5[0]); gm[2]=fmaxf(a5[1][0],a5[1][1]); gm[3]=fmaxf(a5[1][2],a5[1][3]);
      gm[4]=max4(a5[2]); gm[6]=max4(a5[3]); gm[7]=max4(a5[4]);
    }
    #pragma unroll
    for(int g = 0; g < 8; g++){
      float v = gm[g];
      v = fmaxf(v, __shfl_xor(v, 16));
      v = fmaxf(v, __shfl_xor(v, 32));
      gm[g] = v;
    }
    float bias = Wc[SB3_O + col];
    soutT[((size_t)b*NN + n0 + 2*q)*CC + col]     = gm[2*q] + bias;
    soutT[((size_t)b*NN + n0 + 2*q + 1)*CC + col] = gm[2*q+1] + bias;
  }
}

// ---------------- K5: temporal tail v3 — conv3 + fp16 MFMA GEMM + FUSED final ----------------
__global__ __launch_bounds__(256, 4) void k_tout(
    const float* __restrict__ t1t, const float* __restrict__ Wc,
    const ushort_t* __restrict__ Wh3t, const float* __restrict__ soutT,
    const void* __restrict__ xraw, void* __restrict__ outraw){
  __shared__ ushort_t t2s[32][136];
  int b  = blockIdx.y;
  int n0 = blockIdx.x * 32;
  int t  = threadIdx.x;
  const int lane = t & 63, w = t >> 6, l15 = lane & 15, q = lane >> 4;
  const int isf = detect_isf(xraw, lane);
  {
    int o = t & 127;
    int rbase = t >> 7;   // 0 or 1
    float w2v[12];
    #pragma unroll
    for(int z = 0; z < 12; z++) w2v[z] = Wc[TW2_O + o*12 + z];
    float bv = Wc[TB2_O + o];
    int ob = o & ~3;
    for(int e = 0; e < 16; e++){
      int r = rbase + 2*e;
      int n = n0 + r;
      float acc = bv;
      #pragma unroll
      for(int d = 0; d < 3; d++){
        int nn2 = n + d - 1;
        if(nn2 >= 0 && nn2 < NN){
          float4 tv = *(const float4*)(t1t + ((size_t)b*NN + nn2)*WW + ob);
          acc += w2v[0*3+d]*tv.x + w2v[1*3+d]*tv.y + w2v[2*3+d]*tv.z + w2v[3*3+d]*tv.w;
        }
      }
      float vr = fmaxf(acc, 0.f);
      _Float16 h = (_Float16)vr;
      t2s[r][o] = *reinterpret_cast<ushort_t*>(&h);
    }
  }
  __syncthreads();
  #pragma unroll
  for(int nt = 0; nt < 4; nt++){
    const int col = w*64 + nt*16 + l15;
    half8 bf[4];
    #pragma unroll
    for(int k = 0; k < 4; k++)
      bf[k] = *(const half8*)(Wh3t + (size_t)col*WW + k*32 + q*8);
    f32x4 acc[2];
    acc[0] = (f32x4){0.f,0.f,0.f,0.f};
    acc[1] = (f32x4){0.f,0.f,0.f,0.f};
    #pragma unroll
    for(int k = 0; k < 4; k++){
      #pragma unroll
      for(int mt = 0; mt < 2; mt++){
        half8 af = *(const half8*)(&t2s[mt*16 + l15][k*32 + q*8]);
        acc[mt] = __builtin_amdgcn_mfma_f32_16x16x32_f16(af, bf[k], acc[mt], 0, 0, 0);
      }
    }
    float bias = Wc[TB3_O + col];
    #pragma unroll
    for(int mt = 0; mt < 2; mt++){
      int nbase = n0 + mt*16 + 4*q;                 // 4 consecutive n (r=0..3)
      size_t xoff = ((size_t)b*CC + col)*NN + nbase;
      float xv[4];
      if(isf){
        float4 x4 = *(const float4*)((const float*)xraw + xoff);
        xv[0]=x4.x; xv[1]=x4.y; xv[2]=x4.z; xv[3]=x4.w;
      } else {
        const ushort_t* xh = (const ushort_t*)xraw + xoff;
        #pragma unroll
        for(int r = 0; r < 4; r++) xv[r] = bfs(xh[r]);
      }
      float4 v4;
      #pragma unroll
      for(int r = 0; r < 4; r++){
        int n = nbase + r;
        float sv = soutT[((size_t)b*NN + n)*CC + col];
        float comb = sv + acc[mt][r] + bias;
        ((float*)&v4)[r] = fmaxf(comb + xv[r], 0.f);
      }
      if(isf){
        *(float4*)((float*)outraw + xoff) = v4;
      } else {
        *(uint2*)((ushort_t*)outraw + xoff) = f4_to_bf4(v4);
      }
    }
  }
}

extern "C" void kernel_launch(void* const* d_in, const int* in_sizes, int n_in,
                              void* d_out, int out_size, void* d_ws, size_t ws_size,
                              hipStream_t stream){
  char* ws = (char*)d_ws;
  // workspace layout (bytes)
  float*    Wc    = (float*)   (ws + 256);          //    667,648
  float*    xT    = (float*)   (ws + 1048576);      // 33,554,432
  double*   xx    = (double*)  (ws + 34603008);     //    262,144
  float*    xxf   = (float*)   (ws + 34865152);     //    131,072
  int*      idx   = (int*)     (ws + 34996224);     //  1,310,720
  ushort_t* y1h   = (ushort_t*)(ws + 36306944);     //  8,388,608 (fp16)
  float*    y2t   = (float*)   (ws + 53084160);     // 16,777,216
  float*    t1t   = (float*)   (ws + 69861376);     // 16,777,216
  float*    soutT = (float*)   (ws + 86638592);     // 33,554,432
  ushort_t* xTh   = (ushort_t*)(ws + 120193024);    // 16,777,216
  // knnP eliminated (merge fused into k_knn); Wh tables in the old knnP region.
  ushort_t* Wh    = (ushort_t*)(ws + 136970240);    //    196,608
  ushort_t* Wh3   = (ushort_t*)(ws + 137166848);    //     65,536
  ushort_t* Wh3t  = (ushort_t*)(ws + 137232384);    //     65,536

  k_convw<<<dim3(64,12), 256, 0, stream>>>(d_in[0],
                                           d_in[1], d_in[2], d_in[3], d_in[4], d_in[5], d_in[6],
                                           d_in[7], d_in[8], d_in[9], d_in[10], d_in[11], d_in[12],
                                           Wc);
  k_convx<<<dim3(64,8,16), dim3(32,8), 0, stream>>>(d_in[0], xT, xTh);
  k_norms<<<dim3(8192), dim3(256), 0, stream>>>(xT, xx, xxf);
  k_knn<<<dim3(16,32), dim3(256), 0, stream>>>(xTh, xxf, xT, xx, idx);
  k_convwh<<<dim3(640), 256, 0, stream>>>(Wc, Wh, Wh3, Wh3t);
  k_pointwise<<<dim3(32,16), 256, 0, stream>>>(xTh, Wh, Wc, y1h, y2t, t1t);
  k_s3max2<<<dim3(256,16), dim3(256), 0, stream>>>(y1h, y2t, idx, Wc, Wh3, soutT);
  k_tout<<<dim3(64,16), dim3(256), 0, stream>>>(t1t, Wc, Wh3t, soutT, d_in[0], d_out);
}